// Round 8
// baseline (181.009 us; speedup 1.0000x reference)
//
#include <hip/hip_runtime.h>

// Problem constants
#define BB 4
#define CC 32
#define LL 50176              // 224*224
#define KK2 25
#define CDTOT (BB * LL * KK2) // 5,017,600 floats in cd

// out[b,c2,l2] = in[b,c2,l2] * sum_k2 Wt(b,l2,k2) * V(b,n).
// Lanes stride l2 by 800 (l2 = rem + 800*ii, rem wave-uniform).
// KEY IDENTITY: ys*224 + xs = u  =>  unclamped gather addr
//     addr = A0(k2) + ii + 1568*c2,  A0 = c*LL + 224*dy + dx + e0  (WAVE-UNIFORM)
// x-OOB lanes read +-2 off (in-bounds within batch slab) but weight=0.
// => load is uniform_base[ii]: saddr form, 1 VALU + 1 load per MAC, A-table in SGPRs.
// Interior c2 in [1,30] always y-in-bounds; c2=0/31 via clamped special pass.
// Stores PLAIN (R5: nontemporal stores defeated write-combining 25->97MB).
// R6: cd staging via global_load_lds (neutral, saves staging VGPRs).
// R7 FAILED: __launch_bounds__(256,6) -> spill (516us). No forced min-waves.
// R8 FAILED: VGPR 176 + XCD-split store lines -> WRITE 2x.
// R9 FAILED: __launch_bounds__(512,4) acted as blocks/CU -> 64-VGPR spill.
// R10 NEUTRAL-NEG: 8-wide rem tile: clean but 74us. Transactions not the wall.
// R11 FAILED: both-chunks-per-block -> VGPR 176, 127us.
// R12 NEUTRAL-NEG: 2-deep k2 pipeline -> VALU 29->41%, 69us. Per-wave MLP null.
// MEASURED LAW (R6/R10/R11/R12): per-wave lifetime tracks per-wave work at
//     ~84cyc/VMEM-instr, INVARIANT to co-residency and pipeline depth. Fewer+
//     bigger waves ran the law backwards (R11: 2x work -> 2x time). R13 runs
//     it FORWARDS: 2x waves each with half the work.
// R13: 3200 blocks x 256thr, 8 channels (one gg-group) per block. Exact R6
//     chassis otherwise. Chunks {0,1} on even XCD of the batch pair, {2,3}
//     on odd (slot<200 picks sub-chunk) -> a fixed c2's tiles all on one XCD
//     -> 64B store lines stay XCD-pure (R8's trap avoided). cd staging+setup
//     duplicated 4x/tile (+~20MB FETCH, cheap at 14% HBM).

typedef const float __attribute__((address_space(1)))* gcd_ptr;
typedef float __attribute__((address_space(3)))* lds_ptr;

__global__ __launch_bounds__(256) void conv_local_kernel(
    const float* __restrict__ input,
    const float* __restrict__ cd,
    const float* __restrict__ colw,
    const float* __restrict__ posw,
    float* __restrict__ out)
{
    // 6656 floats: staging writes slots [0,6656) (64 rows x 101 + DMA overshoot),
    // rows use 100 of 101 (pad slot = junk). Exchange reuses [0,2560) afterwards.
    __shared__ float smem[6656];

    const int t    = threadIdx.x;
    const int lane = t & 63;
    const int w    = t >> 6;              // wave 0..3 -> rem = rem0 + w

    // XCD-locality swizzle; chunk parity tied to XCD parity for line purity
    const int bx   = blockIdx.x;          // 0..3199
    const int xcd  = bx & 7;
    const int slot = bx >> 3;             // 0..399
    const int b    = xcd >> 1;            // batch pinned to XCD pair
    const int par  = xcd & 1;             // chunk pair: {0,1} or {2,3}
    const int sub  = (slot >= 200);       // which chunk of the pair
    const int tile = slot - sub * 200;    // 0..199
    const int chunk  = par * 2 + sub;     // 0..3 -> c2 in [8*chunk, 8*chunk+8)
    const int rem0   = tile * 4;          // 0..796
    const int c2base = chunk * 8;

    const float cw = colw[0];
    const float pw = posw[0];
    const float* __restrict__ in_b  = input + b * (CC * LL);
    float* __restrict__       out_b = out   + b * (CC * LL);

    // ---- stage cd for this block's 256 l2 values: direct global->LDS DMA ----
    {
        const int cd_base = b * (LL * KK2);
        #pragma unroll
        for (int jj = 0; jj < 26; ++jj) {
            int s    = t + 256 * jj;             // slot in [0, 6656)
            int ci   = s / 101;                  // row 0..65 (>=64 -> junk, clamped)
            int pos  = s - ci * 101;             // (rem-rem0)*25 + k2, or 100 = pad
            int gidx = cd_base + (rem0 + 800 * ci) * KK2 + pos;
            gidx = min(gidx, CDTOT - 1);         // clamp pad/OOB (values unused)
            __builtin_amdgcn_global_load_lds((gcd_ptr)(cd + gidx),
                                             (lds_ptr)(smem + (jj * 256 + w * 64)),
                                             4, 0, 0);
        }
    }
    __syncthreads();   // drains vmcnt -> staged cd visible

    // ---- per-thread setup ----
    const int remU = __builtin_amdgcn_readfirstlane(rem0 + w);  // wave-uniform
    const int ii   = lane;

    float Wt[KK2];   // per-lane weight, x-mask folded in (fp32)
    int   A0u[KK2]; // WAVE-UNIFORM base: c*LL + 224*dy + dx + e0  (-> SGPRs)
    const float POS[KK2] = {8,5,4,5,8, 5,2,1,2,5, 4,1,0,1,4, 5,2,1,2,5, 8,5,4,5,8};

    #pragma unroll
    for (int k2 = 0; k2 < KK2; ++k2) {
        int t1 = 576 * k2 + remU;       // all scalar:
        int q0 = t1 / 800;
        int r  = t1 - q0 * 800;
        int c  = r / 25;
        int s  = r - c * 25;
        int dy = s / 5 - 2;
        int dx = s % 5 - 2;
        int e0 = 62 * k2 + q0;          // <= 1506
        A0u[k2] = c * LL + 224 * dy + dx + e0;
        int u  = e0 + ii;               // vector: +lane
        int ys = u / 224;               // [0,7]
        int xs = u - ys * 224;
        int xm = xs + dx;
        bool xok = (unsigned)xm < 224u;
        float wgt = fmaf(smem[ii * 101 + w * 25 + k2], cw, POS[k2] * pw);
        Wt[k2] = xok ? wgt : 0.0f;      // x-mask folded into weight
    }
    __syncthreads();   // smem reused as exchange buffer from here

    // mapping B (contiguous-l2) constants for coalesced iv-load / store
    const int remB = t & 3;
    const int iiB  = t >> 2;
    const int l2B  = rem0 + remB + 800 * iiB;
    const bool okB = l2B < LL;
    const int idxB = min(l2B, LL - 1);

    // ---- single group of 8 channels ----
    float acc[8], iv[8];
    #pragma unroll
    for (int g = 0; g < 8; ++g) {
        acc[g] = 0.0f;
        iv[g]  = in_b[(c2base + g) * LL + idxB];  // coalesced, overlaps gathers
    }

    // interior gathers: uniform base + lane offset -> saddr loads
    #pragma unroll
    for (int k2 = 0; k2 < KK2; ++k2) {
        const float wv = Wt[k2];
        #pragma unroll
        for (int g = 0; g < 8; ++g) {
            int c2  = c2base + g;
            int c2e = min(max(c2, 1), 30);   // special slots: dummy interior read
            const float* bp = in_b + (A0u[k2] + 1568 * c2e);  // wave-uniform ptr
            acc[g] = fmaf(bp[ii], wv, acc[g]);
        }
    }

    // special channels c2=0 / c2=31: clamped + y-masked pass, OVERWRITES acc
    if (chunk == 0 || chunk == 3) {
        const bool sp0 = (chunk == 0);
        float a = 0.0f;
        #pragma unroll
        for (int k2 = 0; k2 < KK2; ++k2) {
            int t1 = 576 * k2 + remU;
            int q0 = t1 / 800;
            int r  = t1 - q0 * 800;
            int c  = r / 25;
            int s  = r - c * 25;
            int dy = s / 5 - 2;
            int dx = s % 5 - 2;
            int u  = 62 * k2 + q0 + ii;
            int ys = u / 224;
            int xs = u - ys * 224;
            int xc = min(max(xs + dx, 0), 223);
            int yy = ys + dy;                     // [-2, 9]
            int yb = sp0 ? max(yy, 0) : (217 + min(yy, 6));
            bool ok = sp0 ? (yy >= 0) : (yy <= 6);
            float v = in_b[c * LL + yb * 224 + xc];
            a = fmaf(ok ? v : 0.0f, Wt[k2], a);
        }
        if (sp0) acc[0] = a; else acc[7] = a;
    }

    // exchange to mapping B; strides 320/80 -> max 2-way LDS access (free)
    #pragma unroll
    for (int g = 0; g < 8; ++g)
        smem[g * 320 + w * 80 + lane] = acc[g];
    __syncthreads();
    #pragma unroll
    for (int g = 0; g < 8; ++g) {
        float S = smem[g * 320 + remB * 80 + iiB];
        if (okB) out_b[(c2base + g) * LL + idxB] = S * iv[g];  // plain store
    }
}

extern "C" void kernel_launch(void* const* d_in, const int* in_sizes, int n_in,
                              void* d_out, int out_size, void* d_ws, size_t ws_size,
                              hipStream_t stream) {
    const float* input = (const float*)d_in[0];
    const float* cdist = (const float*)d_in[1];
    const float* cwp   = (const float*)d_in[2];
    const float* pwp   = (const float*)d_in[3];
    float* o = (float*)d_out;

    dim3 grid(3200);   // 4 b x 4 chunks x 200 rem0-tiles, XCD-pinned in-kernel
    dim3 block(256);
    hipLaunchKernelGGL(conv_local_kernel, grid, block, 0, stream,
                       input, cdist, cwp, pwp, o);
}

// Round 9
// 157.638 us; speedup vs baseline: 1.1483x; 1.1483x over previous
//
#include <hip/hip_runtime.h>

// Problem constants
#define BB 4
#define CC 32
#define LL 50176              // 224*224
#define KK2 25
#define CDTOT (BB * LL * KK2) // 5,017,600 floats in cd

// out[b,c2,l2] = in[b,c2,l2] * sum_k2 Wt(b,l2,k2) * V(b,n).
// KEY IDENTITY: per (k2, c2, wave) the 64 gather addresses are CONSECUTIVE:
//     addr = A0u[k2] + 1568*c2 + ii, A0u wave-uniform -> saddr loads.
// Interior c2 in [1,30] always in-bounds; c2=0/31 via clamped special pass.
// Stores PLAIN (R5). cd staged via global_load_lds (R6).
// R7 FAILED: forced min-waves -> spill. R8 FAILED: VGPR176 + XCD-split lines.
// R9 FAILED: launch_bounds(512,4) = blocks/CU -> spill.
// R10/R12 NEUTRAL: fewer mapB lines / 2-deep pipeline -> no change.
// R11/R13 FAILED: residency collapsed (VGPR 176/148).
// MEASURED LAW (R6..R13): GPU-wide VMEM wave-instr throughput tops at
//     ~42 instr/us (~15 cyc/instr of CU-shared vector-mem pipe), saturated
//     at ~5.7 resident waves/CU. Latency depth, occupancy beyond that, and
//     line counts are all irrelevant. Only VMEM INSTRUCTION COUNT matters.
// R14: FLOAT2 GATHERS. Lane (hi=lane>>5, m=lane&31) loads 8B = u-offsets
//     {2m,2m+1} of channel 2g'+hi: one instr feeds 2 channels x 64 offsets
//     -> gathers 400->200/wave (total VMEM 483->~283). Per-lane weight pair
//     moves to LDS (wlds[w][k2][ii], written in the verbatim setup loop,
//     read as one broadcast float2/k2). Misaligned (4B) float2 accepted.
//     Special c2=0/31: per-pair offset select makes dummy lanes read an
//     interior channel; their rows are overwritten by the special pass.
//     Exchange read / iv / stores / staging byte-identical to R6.

typedef const float __attribute__((address_space(1)))* gcd_ptr;
typedef float __attribute__((address_space(3)))* lds_ptr;

#define WOFF 6656   // wlds base (floats): wlds[w][k2][ii] = WOFF + w*1600 + k2*64 + ii

__global__ __launch_bounds__(256) void conv_local_kernel(
    const float* __restrict__ input,
    const float* __restrict__ cd,
    const float* __restrict__ colw,
    const float* __restrict__ posw,
    float* __restrict__ out)
{
    // [0,6656): cd staging, reused as exchange [0,5120) after setup.
    // [6656,13056): per-wave weight table wlds (4 waves x 25 k2 x 64 ii).
    __shared__ float smem[13056];

    const int t    = threadIdx.x;
    const int lane = t & 63;
    const int w    = t >> 6;              // wave 0..3 -> rem = rem0 + w

    // XCD-locality swizzle (validated R3: FETCH 211->42MB)
    const int bx   = blockIdx.x;          // 0..1599
    const int xcd  = bx & 7;
    const int slot = bx >> 3;             // 0..199
    const int b    = xcd >> 1;            // batch pinned to XCD pair
    const int j    = slot * 2 + (xcd & 1);// 0..399 within batch
    const int chunk  = j & 1;             // c2-chunk: [0,16) or [16,32)
    const int rem0   = (j >> 1) * 4;      // 0..796
    const int c2base = chunk * 16;

    const float cw = colw[0];
    const float pw = posw[0];
    const float* __restrict__ in_b  = input + b * (CC * LL);
    float* __restrict__       out_b = out   + b * (CC * LL);

    // ---- stage cd for this block's 256 l2 values: direct global->LDS DMA ----
    {
        const int cd_base = b * (LL * KK2);
        #pragma unroll
        for (int jj = 0; jj < 26; ++jj) {
            int s    = t + 256 * jj;             // slot in [0, 6656)
            int ci   = s / 101;                  // row 0..65 (>=64 -> junk, clamped)
            int pos  = s - ci * 101;             // (rem-rem0)*25 + k2, or 100 = pad
            int gidx = cd_base + (rem0 + 800 * ci) * KK2 + pos;
            gidx = min(gidx, CDTOT - 1);         // clamp pad/OOB (values unused)
            __builtin_amdgcn_global_load_lds((gcd_ptr)(cd + gidx),
                                             (lds_ptr)(smem + (jj * 256 + w * 64)),
                                             4, 0, 0);
        }
    }
    __syncthreads();   // drains vmcnt -> staged cd visible

    // ---- per-thread setup (verbatim R6 math; Wt redirected to LDS) ----
    const int remU = __builtin_amdgcn_readfirstlane(rem0 + w);  // wave-uniform
    const int ii   = lane;

    int A0u[KK2];   // WAVE-UNIFORM base: c*LL + 224*dy + dx + e0  (-> SGPRs)
    const float POS[KK2] = {8,5,4,5,8, 5,2,1,2,5, 4,1,0,1,4, 5,2,1,2,5, 8,5,4,5,8};

    #pragma unroll
    for (int k2 = 0; k2 < KK2; ++k2) {
        int t1 = 576 * k2 + remU;       // all scalar:
        int q0 = t1 / 800;
        int r  = t1 - q0 * 800;
        int c  = r / 25;
        int s  = r - c * 25;
        int dy = s / 5 - 2;
        int dx = s % 5 - 2;
        int e0 = 62 * k2 + q0;          // <= 1506
        A0u[k2] = c * LL + 224 * dy + dx + e0;
        int u  = e0 + ii;               // vector: +lane
        int ys = u / 224;               // [0,7]
        int xs = u - ys * 224;
        int xm = xs + dx;
        bool xok = (unsigned)xm < 224u;
        float wgt = fmaf(smem[ii * 101 + w * 25 + k2], cw, POS[k2] * pw);
        smem[WOFF + w * 1600 + k2 * 64 + ii] = xok ? wgt : 0.0f;  // x-mask folded
    }
    __syncthreads();   // staging region reused as exchange from here

    // mapping B (contiguous-l2) constants for coalesced iv-load / store
    const int remB = t & 3;
    const int iiB  = t >> 2;
    const int l2B  = rem0 + remB + 800 * iiB;
    const bool okB = l2B < LL;
    const int idxB = min(l2B, LL - 1);

    // float2-gather lane decomposition
    const int m  = lane & 31;             // offset pair index: u-offsets {2m,2m+1}
    const int hi = lane >> 5;             // channel parity within pair
    const int voffN  = 1568 * hi + 2 * m; // normal: channel 2g'+hi
    const int voffLo = 1568 + 2 * m;      // special pair (0,1): all lanes read c2=1
    const int voffHi = 2 * m;             // special pair (30,31): all lanes read c2=30

    // ---- main loop: 2 groups of 8 channels (4 float2-pairs each) ----
    #pragma unroll 1
    for (int gg = 0; gg < 2; ++gg) {
        float acc0[4], acc1[4], iv[8];
        #pragma unroll
        for (int gp = 0; gp < 4; ++gp) { acc0[gp] = 0.0f; acc1[gp] = 0.0f; }
        #pragma unroll
        for (int g = 0; g < 8; ++g)
            iv[g] = in_b[(c2base + gg * 8 + g) * LL + idxB];  // coalesced, overlaps gathers

        // interior gathers: 25 k2 x 4 channel-pairs, one dwordx2 each
        #pragma unroll
        for (int k2 = 0; k2 < KK2; ++k2) {
            const float2 wp = *(const float2*)&smem[WOFF + w * 1600 + k2 * 64 + 2 * m];
            #pragma unroll
            for (int gp = 0; gp < 4; ++gp) {
                // per-pair offset select handles the c2=0/31 dummy reads
                const bool spLo = (chunk == 0) && (gg == 0) && (gp == 0);
                const bool spHi = (chunk == 1) && (gg == 1) && (gp == 3);
                const int offE = spLo ? voffLo : (spHi ? voffHi : voffN);
                const float* bp = in_b + (A0u[k2] + 1568 * (c2base + gg * 8 + 2 * gp));
                const float2 v = *(const float2*)(bp + offE);
                acc0[gp] = fmaf(v.x, wp.x, acc0[gp]);
                acc1[gp] = fmaf(v.y, wp.y, acc1[gp]);
            }
        }

        // exchange to mapping B: lane (hi,m) owns channel 2gp+hi, offsets 2m,2m+1
        float* sbuf = smem + (gg & 1) * 2560;
        #pragma unroll
        for (int gp = 0; gp < 4; ++gp) {
            const int gl = 2 * gp + hi;
            *(float2*)&sbuf[gl * 320 + w * 80 + 2 * m] = make_float2(acc0[gp], acc1[gp]);
        }

        // special channels c2=0 / c2=31: clamped + y-masked pass, writes its
        // row directly (overwrites the dummy-gather garbage, same-wave order)
        const bool sp_here = (chunk == 0) ? (gg == 0) : (gg == 1);
        if (sp_here) {
            const bool sp0 = (chunk == 0);
            float a = 0.0f;
            #pragma unroll
            for (int k2 = 0; k2 < KK2; ++k2) {
                int t1 = 576 * k2 + remU;
                int q0 = t1 / 800;
                int r  = t1 - q0 * 800;
                int c  = r / 25;
                int s  = r - c * 25;
                int dy = s / 5 - 2;
                int dx = s % 5 - 2;
                int u  = 62 * k2 + q0 + ii;
                int ys = u / 224;
                int xs = u - ys * 224;
                int xc = min(max(xs + dx, 0), 223);
                int yy = ys + dy;                     // [-2, 9]
                int yb = sp0 ? max(yy, 0) : (217 + min(yy, 6));
                bool ok = sp0 ? (yy >= 0) : (yy <= 6);
                float v = in_b[c * LL + yb * 224 + xc];
                float wk = smem[WOFF + w * 1600 + k2 * 64 + ii];
                a = fmaf(ok ? v : 0.0f, wk, a);
            }
            sbuf[(sp0 ? 0 : 7) * 320 + w * 80 + lane] = a;
        }
        __syncthreads();

        // mapping-B read + store (byte-identical to R6)
        #pragma unroll
        for (int g = 0; g < 8; ++g) {
            float S = sbuf[g * 320 + remB * 80 + iiB];
            if (okB) out_b[(c2base + gg * 8 + g) * LL + idxB] = S * iv[g];  // plain store
        }
        // no trailing barrier: gg=1 uses a disjoint sbuf region
    }
}

extern "C" void kernel_launch(void* const* d_in, const int* in_sizes, int n_in,
                              void* d_out, int out_size, void* d_ws, size_t ws_size,
                              hipStream_t stream) {
    const float* input = (const float*)d_in[0];
    const float* cdist = (const float*)d_in[1];
    const float* cwp   = (const float*)d_in[2];
    const float* pwp   = (const float*)d_in[3];
    float* o = (float*)d_out;

    dim3 grid(1600);   // 4 b x 2 chunks x 200 rem0-tiles, XCD-pinned in-kernel
    dim3 block(256);
    hipLaunchKernelGGL(conv_local_kernel, grid, block, 0, stream,
                       input, cdist, cwp, pwp, o);
}